// Round 8
// baseline (434.922 us; speedup 1.0000x reference)
//
#include <hip/hip_runtime.h>
#include <hip/hip_bf16.h>
#include <float.h>
#include <stdint.h>

#define BATCH 4096
#define NLEAF 50000
#define DIM   256
#define BN    128
#define NTILES 391                 /* ceil(50000/128) */
#define NGRP  (NTILES * 8)         /* 3128 16-leaf groups */
#define MAXC  128                  /* candidate-group cap per row */
#define NCHUNK 8
#define GPC   ((NGRP + NCHUNK - 1) / NCHUNK)   /* 391 groups per chunk */

typedef _Float16 h8  __attribute__((ext_vector_type(8)));
typedef float    f16v __attribute__((ext_vector_type(16)));

// ---------- helpers ----------
__device__ __forceinline__ float h2f(unsigned short u) {
    return (float)__builtin_bit_cast(_Float16, u);
}

__device__ __forceinline__ void insert5v(float key, float (&k)[5]) {
    if (key < k[4]) {
        if (key < k[3]) { k[4]=k[3];
            if (key < k[2]) { k[3]=k[2];
                if (key < k[1]) { k[2]=k[1];
                    if (key < k[0]) { k[1]=k[0]; k[0]=key; } else k[1]=key;
                } else k[2]=key;
            } else k[3]=key;
        } else k[4]=key;
    }
}

__device__ __forceinline__ bool lexless(float k, int i, float K, int I) {
    return (k < K) || (k == K && i < I);
}
__device__ __forceinline__ void insert5lex(float key, int id, float (&k)[5], int (&ix)[5]) {
    if (lexless(key, id, k[4], ix[4])) {
        if (lexless(key, id, k[3], ix[3])) { k[4]=k[3]; ix[4]=ix[3];
            if (lexless(key, id, k[2], ix[2])) { k[3]=k[2]; ix[3]=ix[2];
                if (lexless(key, id, k[1], ix[1])) { k[2]=k[1]; ix[2]=ix[1];
                    if (lexless(key, id, k[0], ix[0])) { k[1]=k[0]; ix[1]=ix[0]; k[0]=key; ix[0]=id; }
                    else { k[1]=key; ix[1]=id; }
                } else { k[2]=key; ix[2]=id; }
            } else { k[3]=key; ix[3]=id; }
        } else { k[4]=key; ix[4]=id; }
    }
}

__device__ __forceinline__ void gload_lds16(const void* g, void* l) {
    __builtin_amdgcn_global_load_lds(
        (const __attribute__((address_space(1))) uint32_t*)g,
        (__attribute__((address_space(3))) uint32_t*)l, 16, 0, 0);
}

// ---------- kernel 0: norms + fp32->fp16 convert (fused) ----------
__global__ void norms_cvt_k(const float* __restrict__ z, const float* __restrict__ leaf,
                            float* __restrict__ x2, float* __restrict__ afac,
                            float* __restrict__ y2, float* __restrict__ bfac,
                            unsigned short* __restrict__ zf, unsigned short* __restrict__ lf) {
    int wv = (blockIdx.x * 256 + threadIdx.x) >> 6;
    int l = threadIdx.x & 63;
    if (wv >= BATCH + NLEAF) return;
    bool isz = wv < BATCH;
    const float* row = isz ? z + (size_t)wv * DIM : leaf + (size_t)(wv - BATCH) * DIM;
    float4 v = reinterpret_cast<const float4*>(row)[l];
    _Float16 h0 = (_Float16)v.x, h1 = (_Float16)v.y, h2 = (_Float16)v.z, h3 = (_Float16)v.w;
    ushort4 u;
    u.x = __builtin_bit_cast(unsigned short, h0);
    u.y = __builtin_bit_cast(unsigned short, h1);
    u.z = __builtin_bit_cast(unsigned short, h2);
    u.w = __builtin_bit_cast(unsigned short, h3);
    unsigned short* dst = isz ? zf + (size_t)wv * DIM : lf + (size_t)(wv - BATCH) * DIM;
    reinterpret_cast<ushort4*>(dst)[l] = u;
    float s = v.x*v.x + v.y*v.y + v.z*v.z + v.w*v.w;
#pragma unroll
    for (int off = 32; off > 0; off >>= 1) s += __shfl_down(s, off, 64);
    if (l == 0) {
        if (isz) { x2[wv] = s; afac[wv] = 2.0f / (1.0f - s); }
        else { int j = wv - BATCH; y2[j] = s; bfac[j] = 1.0f / (1.0f - s); }
    }
}

// ---------- kernel 1: single-pass fp16 MFMA GEMM + per-16-leaf-group min ----------
// 128x128 tile, BK=64, 32x32x16 MFMA with SWAPPED operands: D[leaf][z].
// XCD slab: xcd = bid&7 owns n-tiles [xcd*49, ...); within, M-major.
__global__ __launch_bounds__(256, 2) void gemm_min_k(
        const unsigned short* __restrict__ zf, const unsigned short* __restrict__ lf,
        const float* __restrict__ x2, const float* __restrict__ y2,
        const float* __restrict__ bfac, unsigned short* __restrict__ mins) {
    extern __shared__ char sm[];
    float2* ybt = (float2*)(sm + 65536);   // per-leaf (bfac, y2*bfac), 128 pairs
    float*  xt  = (float*)(sm + 66560);    // per-z x2, 128

    const int t = threadIdx.x;
    const int w = t >> 6, l = t & 63;
    const int wr = w >> 1, wc = w & 1;
    const int l31 = l & 31, lg2 = l >> 5;

    const int bid = blockIdx.x;
    const int xcd = bid & 7, q = bid >> 3;
    const int ntile = xcd * 49 + (q >> 5);
    if (ntile >= NTILES) return;
    const int m0 = (q & 31) * 128;
    const int l0 = ntile * BN;

    if (t < 128) {
        xt[t] = x2[m0 + t];
        int gl = l0 + t;
        bool v = gl < NLEAF;
        float bb = v ? bfac[gl] : 0.0f;
        float yy = v ? y2[gl] : 0.0f;
        ybt[t] = make_float2(bb, v ? yy * bb : 1e30f);   // pad -> key = 1e30
    }

    // staging source offsets (bytes): involution swizzle slot^ (row&7)
    int srcA[4], srcB[4];
#pragma unroll
    for (int j = 0; j < 4; ++j) {
        int slot = j * 256 + t;
        int row = slot >> 3, sl = slot & 7;
        int swz = sl ^ (row & 7);
        srcA[j] = (m0 + row) * 512 + swz * 16;
        int gl = l0 + row; if (gl > NLEAF - 1) gl = NLEAF - 1;
        srcB[j] = gl * 512 + swz * 16;
    }

    f16v acc[2][2];
#pragma unroll
    for (int i = 0; i < 2; ++i)
#pragma unroll
        for (int j = 0; j < 2; ++j)
#pragma unroll
            for (int r = 0; r < 16; ++r) acc[i][j][r] = 0.0f;

    auto stage = [&](int ks, int bsel) {
        char* dst = sm + bsel * 32768;
        const int kb = ks * 128;
#pragma unroll
        for (int j = 0; j < 4; ++j) {
            gload_lds16((const char*)zf + srcA[j] + kb, dst + (j * 256 + w * 64) * 16);
            gload_lds16((const char*)lf + srcB[j] + kb, dst + 16384 + (j * 256 + w * 64) * 16);
        }
    };

    auto compute = [&](int bsel) {
        const char* Ab = sm + bsel * 32768;
        const char* Bb = Ab + 16384;
#pragma unroll
        for (int kk = 0; kk < 4; ++kk) {
            const int cz = kk * 32 + lg2 * 16;
            h8 za[2], lb[2];
#pragma unroll
            for (int f = 0; f < 2; ++f) {
                int ra = wr * 64 + f * 32 + l31;
                za[f] = *(const h8*)(Ab + ra * 128 + (cz ^ ((ra & 7) << 4)));
                int rb = wc * 64 + f * 32 + l31;
                lb[f] = *(const h8*)(Bb + rb * 128 + (cz ^ ((rb & 7) << 4)));
            }
#pragma unroll
            for (int fi = 0; fi < 2; ++fi)
#pragma unroll
                for (int fj = 0; fj < 2; ++fj)
                    acc[fi][fj] = __builtin_amdgcn_mfma_f32_32x32x16_f16(lb[fj], za[fi], acc[fi][fj], 0, 0, 0);
        }
    };

    stage(0, 0);
    __syncthreads();
#pragma unroll
    for (int ks = 0; ks < 4; ++ks) {
        if (ks < 3) stage(ks + 1, (ks + 1) & 1);
        compute(ks & 1);
        __syncthreads();
    }

    // epilogue: key = (x2 + y2 - 2*dot)*bfac = fmaf(b, xv - 2a, y2*b); 16-leaf group min
    // Fragment map: z = m0 + wr*64 + fi*32 + l31,
    // leaf = l0 + wc*64 + fj*32 + (reg&3)+8*(reg>>2)+4*lg2 (+16*hi folded into reg).
    float xv[2] = { xt[wr * 64 + l31], xt[wr * 64 + 32 + l31] };
#pragma unroll
    for (int fi = 0; fi < 2; ++fi)
#pragma unroll
        for (int fj = 0; fj < 2; ++fj)
#pragma unroll
            for (int hi = 0; hi < 2; ++hi) {
                float kx[8];
#pragma unroll
                for (int r8 = 0; r8 < 8; ++r8) {
                    int reg = hi * 8 + r8;
                    int L = wc * 64 + fj * 32 + (r8 & 3) + 8 * (r8 >> 2) + 4 * lg2 + 16 * hi;
                    float2 p = ybt[L];
                    float a = acc[fi][fj][reg];
                    kx[r8] = fmaf(p.x, fmaf(-2.0f, a, xv[fi]), p.y);
                }
                float gm = fminf(fminf(fminf(kx[0], kx[1]), fminf(kx[2], kx[3])),
                                 fminf(fminf(kx[4], kx[5]), fminf(kx[6], kx[7])));
                gm = fminf(gm, __shfl_xor(gm, 32, 64));
                if (lg2 == 0) {
                    int g = ntile * 8 + wc * 4 + fj * 2 + hi;
                    _Float16 hgm = (_Float16)fminf(gm, 60000.0f);   // pad -> 6e4, never selected
                    mins[(size_t)g * BATCH + m0 + wr * 64 + fi * 32 + l31] =
                        __builtin_bit_cast(unsigned short, hgm);
                }
            }
}

// ---------- kernel 2a: partial per-(row,chunk) top-5 of group mins ----------
// grid (64 rowblocks, NCHUNK), 256 threads; lane = row, wave = quarter-chunk.
__global__ __launch_bounds__(256) void select1_k(const unsigned short* __restrict__ mins,
                                                 float* __restrict__ part5) {
    __shared__ float sm5[4][64][5];
    const int w = threadIdx.x >> 6, l = threadIdx.x & 63;
    const int row = blockIdx.x * 64 + l;
    const int jb = w * ((GPC + 3) / 4);                 // 98 per wave
    const int je = min(GPC, jb + (GPC + 3) / 4);
    float t5[5] = {FLT_MAX, FLT_MAX, FLT_MAX, FLT_MAX, FLT_MAX};
    int j = jb;
    for (; j + 4 <= je; j += 4) {
        int g = blockIdx.y * GPC + j;
        float a0 = (g     < NGRP) ? h2f(mins[(size_t)g * BATCH + row]) : FLT_MAX;
        float a1 = (g + 1 < NGRP) ? h2f(mins[(size_t)(g + 1) * BATCH + row]) : FLT_MAX;
        float a2 = (g + 2 < NGRP) ? h2f(mins[(size_t)(g + 2) * BATCH + row]) : FLT_MAX;
        float a3 = (g + 3 < NGRP) ? h2f(mins[(size_t)(g + 3) * BATCH + row]) : FLT_MAX;
        float m4 = fminf(fminf(a0, a1), fminf(a2, a3));
        if (m4 < t5[4]) {       // pre-filter: skip the dependent insert chain usually
            insert5v(a0, t5); insert5v(a1, t5); insert5v(a2, t5); insert5v(a3, t5);
        }
    }
    for (; j < je; ++j) {
        int g = blockIdx.y * GPC + j;
        float a = (g < NGRP) ? h2f(mins[(size_t)g * BATCH + row]) : FLT_MAX;
        insert5v(a, t5);
    }
#pragma unroll
    for (int q = 0; q < 5; ++q) sm5[w][l][q] = t5[q];
    __syncthreads();
    if (w == 0) {
#pragma unroll
        for (int ww = 1; ww < 4; ++ww)
#pragma unroll
            for (int q = 0; q < 5; ++q) insert5v(sm5[ww][l][q], t5);
#pragma unroll
        for (int q = 0; q < 5; ++q)
            part5[((size_t)row * NCHUNK + blockIdx.y) * 5 + q] = t5[q];
    }
}

// ---------- kernel 2b: merge chunk top-5s -> per-row threshold; zero cnt ----------
__global__ void select_merge_k(const float* __restrict__ part5,
                               float* __restrict__ rowthr, int* __restrict__ cnt) {
    int row = blockIdx.x * 256 + threadIdx.x;
    if (row >= BATCH) return;
    float t5[5] = {FLT_MAX, FLT_MAX, FLT_MAX, FLT_MAX, FLT_MAX};
    const float* p = part5 + (size_t)row * NCHUNK * 5;
    for (int s = 0; s < NCHUNK * 5; ++s) insert5v(p[s], t5);
    // margin: fp16-input filter err <=8.3e-3/side + fp16 mins storage (rel term)
    rowthr[row] = t5[4] + 2e-3f * fabsf(t5[4]) + 1.8e-2f;
    cnt[row] = 0;
}

// ---------- kernel 2c: candidate scan (atomic append, order-free) ----------
__global__ __launch_bounds__(256) void select_scan_k(const unsigned short* __restrict__ mins,
                                                     const float* __restrict__ rowthr,
                                                     int* __restrict__ cnt,
                                                     int* __restrict__ cand) {
    const int w = threadIdx.x >> 6, l = threadIdx.x & 63;
    const int row = blockIdx.x * 64 + l;
    const float thr = rowthr[row];
    const int jb = w * ((GPC + 3) / 4);
    const int je = min(GPC, jb + (GPC + 3) / 4);
    for (int j = jb; j < je; ++j) {
        int g = blockIdx.y * GPC + j;
        if (g >= NGRP) break;
        float m = h2f(mins[(size_t)g * BATCH + row]);
        if (m <= thr) {
            int c = atomicAdd(&cnt[row], 1);
            if (c < MAXC) cand[row * MAXC + c] = g;
        }
    }
}

// ---------- kernel 3: exact fp32 recheck of candidate groups + outputs ----------
__global__ __launch_bounds__(512) void recheck_k(
        const float* __restrict__ z, const float* __restrict__ leaf,
        const float* __restrict__ x2, const float* __restrict__ y2,
        const float* __restrict__ bfac, const float* __restrict__ afac,
        const int* __restrict__ cnt, const int* __restrict__ cand,
        const int* __restrict__ ids, const float* __restrict__ thr,
        float* __restrict__ out) {
    __shared__ float mk[40];
    __shared__ int   mi[40];
    const int row = blockIdx.x;
    const int t = threadIdx.x, w = t >> 6, l = t & 63;
    float4 zr = *(const float4*)(z + (size_t)row * DIM + l * 4);
    const float x2r = x2[row];
    int nc = cnt[row]; if (nc > MAXC) nc = MAXC;
    float k5[5]; int i5[5];
#pragma unroll
    for (int q = 0; q < 5; ++q) { k5[q] = FLT_MAX; i5[q] = 0x7FFFFFFF; }
    for (int ci = w; ci < nc; ci += 8) {
        int g = cand[row * MAXC + ci];
#pragma unroll 4
        for (int jj = 0; jj < 16; ++jj) {
            int id = g * 16 + jj;
            int idc = (id < NLEAF) ? id : (NLEAF - 1);
            float4 lfv = *(const float4*)(leaf + (size_t)idc * DIM + l * 4);
            float d = zr.x * lfv.x;
            d = fmaf(zr.y, lfv.y, d); d = fmaf(zr.z, lfv.z, d); d = fmaf(zr.w, lfv.w, d);
#pragma unroll
            for (int s = 1; s < 64; s <<= 1) d += __shfl_xor(d, s, 64);
            float sq = fmaxf(x2r + y2[idc] - 2.0f * d, 0.0f);
            float key = (id < NLEAF) ? sq * bfac[idc] : FLT_MAX;
            insert5lex(key, (id < NLEAF) ? id : 0x7FFFFFFF, k5, i5);
        }
    }
    if (l == 0) {
#pragma unroll
        for (int q = 0; q < 5; ++q) { mk[w * 5 + q] = k5[q]; mi[w * 5 + q] = i5[q]; }
    }
    __syncthreads();
    if (t == 0) {
        float fk[5]; int fi[5];
#pragma unroll
        for (int q = 0; q < 5; ++q) { fk[q] = FLT_MAX; fi[q] = 0x7FFFFFFF; }
        for (int s = 0; s < 40; ++s) insert5lex(mk[s], mi[s], fk, fi);
        float u = fk[0] * afac[row];
        u = fmaxf(u, 1e-7f);
        float dd = log1pf(u + sqrtf(u * (u + 2.0f)));
        out[row] = dd;
        out[BATCH + row] = (dd > thr[0]) ? 1.0f : 0.0f;
#pragma unroll
        for (int q = 0; q < 5; ++q)
            out[2 * BATCH + (size_t)row * 5 + q] = (float)ids[fi[q]];
    }
}

extern "C" void kernel_launch(void* const* d_in, const int* in_sizes, int n_in,
                              void* d_out, int out_size, void* d_ws, size_t ws_size,
                              hipStream_t stream) {
    const float* z    = (const float*)d_in[0];
    const float* leaf = (const float*)d_in[1];
    const int*   ids  = (const int*)d_in[2];
    const float* thr  = (const float*)d_in[3];
    float* out = (float*)d_out;

    char* ws = (char*)d_ws;
    float* x2   = (float*)(ws + 0);                 // 16 KB
    float* afac = (float*)(ws + 16384);             // 16 KB
    float* y2   = (float*)(ws + 32768);             // 200 KB
    float* bfac = (float*)(ws + 232768);            // 200 KB
    unsigned short* zf = (unsigned short*)(ws + 432768);     // 2 MB
    unsigned short* lf = (unsigned short*)(ws + 2529920);    // 25.6 MB
    unsigned short* mins = (unsigned short*)(ws + 28129920); // NGRP*4096*2 = 25.6 MB
    int* cnt  = (int*)(ws + 79379072);              // 16 KB
    int* cand = (int*)(ws + 79395456);              // 4096*128*4 = 2 MB
    float* part5  = (float*)(ws + 81492608);        // 4096*8*5*4 = 655 KB
    float* rowthr = (float*)(ws + 82147968);        // 16 KB

    norms_cvt_k<<<(BATCH + NLEAF + 3) / 4, 256, 0, stream>>>(z, leaf, x2, afac, y2, bfac, zf, lf);
    gemm_min_k<<<8 * 49 * 32, 256, 67072, stream>>>(zf, lf, x2, y2, bfac, mins);
    select1_k<<<dim3(BATCH / 64, NCHUNK), 256, 0, stream>>>(mins, part5);
    select_merge_k<<<(BATCH + 255) / 256, 256, 0, stream>>>(part5, rowthr, cnt);
    select_scan_k<<<dim3(BATCH / 64, NCHUNK), 256, 0, stream>>>(mins, rowthr, cnt, cand);
    recheck_k<<<BATCH, 512, 0, stream>>>(z, leaf, x2, y2, bfac, afac, cnt, cand, ids, thr, out);
}

// Round 9
// 386.454 us; speedup vs baseline: 1.1254x; 1.1254x over previous
//
#include <hip/hip_runtime.h>
#include <hip/hip_bf16.h>
#include <float.h>
#include <stdint.h>

#define BATCH 4096
#define NLEAF 50000
#define DIM   256
#define BN    128
#define NTILES 391                 /* ceil(50000/128) */
#define NGRP  (NTILES * 8)         /* 3128 16-leaf groups */
#define MAXC  128                  /* candidate-group cap per row */
#define GCAP  2048                 /* rows per group cap (overflow -> fallback) */
#define NCHUNK 8
#define GPC   ((NGRP + NCHUNK - 1) / NCHUNK)   /* 391 groups per chunk */

typedef _Float16 h8  __attribute__((ext_vector_type(8)));
typedef float    f16v __attribute__((ext_vector_type(16)));
typedef unsigned long long u64;

// ---------- helpers ----------
__device__ __forceinline__ float h2f(unsigned short u) {
    return (float)__builtin_bit_cast(_Float16, u);
}

__device__ __forceinline__ void insert5v(float key, float (&k)[5]) {
    if (key < k[4]) {
        if (key < k[3]) { k[4]=k[3];
            if (key < k[2]) { k[3]=k[2];
                if (key < k[1]) { k[2]=k[1];
                    if (key < k[0]) { k[1]=k[0]; k[0]=key; } else k[1]=key;
                } else k[2]=key;
            } else k[3]=key;
        } else k[4]=key;
    }
}

__device__ __forceinline__ void insert5u(u64 key, u64 (&k)[5]) {
    if (key < k[4]) {
        if (key < k[3]) { k[4]=k[3];
            if (key < k[2]) { k[3]=k[2];
                if (key < k[1]) { k[2]=k[1];
                    if (key < k[0]) { k[1]=k[0]; k[0]=key; } else k[1]=key;
                } else k[2]=key;
            } else k[3]=key;
        } else k[4]=key;
    }
}

__device__ __forceinline__ bool lexless(float k, int i, float K, int I) {
    return (k < K) || (k == K && i < I);
}
__device__ __forceinline__ void insert5lex(float key, int id, float (&k)[5], int (&ix)[5]) {
    if (lexless(key, id, k[4], ix[4])) {
        if (lexless(key, id, k[3], ix[3])) { k[4]=k[3]; ix[4]=ix[3];
            if (lexless(key, id, k[2], ix[2])) { k[3]=k[2]; ix[3]=ix[2];
                if (lexless(key, id, k[1], ix[1])) { k[2]=k[1]; ix[2]=ix[1];
                    if (lexless(key, id, k[0], ix[0])) { k[1]=k[0]; ix[1]=ix[0]; k[0]=key; ix[0]=id; }
                    else { k[1]=key; ix[1]=id; }
                } else { k[2]=key; ix[2]=id; }
            } else { k[3]=key; ix[3]=id; }
        } else { k[4]=key; ix[4]=id; }
    }
}

__device__ __forceinline__ u64 umin64(u64 a, u64 b) { return a < b ? a : b; }
__device__ __forceinline__ u64 umax64(u64 a, u64 b) { return a > b ? a : b; }

__device__ __forceinline__ void gload_lds16(const void* g, void* l) {
    __builtin_amdgcn_global_load_lds(
        (const __attribute__((address_space(1))) uint32_t*)g,
        (__attribute__((address_space(3))) uint32_t*)l, 16, 0, 0);
}

// ---------- kernel 0: norms + fp32->fp16 convert (fused) ----------
__global__ void norms_cvt_k(const float* __restrict__ z, const float* __restrict__ leaf,
                            float* __restrict__ x2, float* __restrict__ afac,
                            float* __restrict__ y2, float* __restrict__ bfac,
                            unsigned short* __restrict__ zf, unsigned short* __restrict__ lf) {
    int wv = (blockIdx.x * 256 + threadIdx.x) >> 6;
    int l = threadIdx.x & 63;
    if (wv >= BATCH + NLEAF) return;
    bool isz = wv < BATCH;
    const float* row = isz ? z + (size_t)wv * DIM : leaf + (size_t)(wv - BATCH) * DIM;
    float4 v = reinterpret_cast<const float4*>(row)[l];
    _Float16 h0 = (_Float16)v.x, h1 = (_Float16)v.y, h2 = (_Float16)v.z, h3 = (_Float16)v.w;
    ushort4 u;
    u.x = __builtin_bit_cast(unsigned short, h0);
    u.y = __builtin_bit_cast(unsigned short, h1);
    u.z = __builtin_bit_cast(unsigned short, h2);
    u.w = __builtin_bit_cast(unsigned short, h3);
    unsigned short* dst = isz ? zf + (size_t)wv * DIM : lf + (size_t)(wv - BATCH) * DIM;
    reinterpret_cast<ushort4*>(dst)[l] = u;
    float s = v.x*v.x + v.y*v.y + v.z*v.z + v.w*v.w;
#pragma unroll
    for (int off = 32; off > 0; off >>= 1) s += __shfl_down(s, off, 64);
    if (l == 0) {
        if (isz) { x2[wv] = s; afac[wv] = 2.0f / (1.0f - s); }
        else { int j = wv - BATCH; y2[j] = s; bfac[j] = 1.0f / (1.0f - s); }
    }
}

// ---------- kernel 1: single-pass fp16 MFMA GEMM + per-16-leaf-group min ----------
__global__ __launch_bounds__(256, 2) void gemm_min_k(
        const unsigned short* __restrict__ zf, const unsigned short* __restrict__ lf,
        const float* __restrict__ x2, const float* __restrict__ y2,
        const float* __restrict__ bfac, unsigned short* __restrict__ mins) {
    extern __shared__ char sm[];
    float2* ybt = (float2*)(sm + 65536);
    float*  xt  = (float*)(sm + 66560);

    const int t = threadIdx.x;
    const int w = t >> 6, l = t & 63;
    const int wr = w >> 1, wc = w & 1;
    const int l31 = l & 31, lg2 = l >> 5;

    const int bid = blockIdx.x;
    const int xcd = bid & 7, q = bid >> 3;
    const int ntile = xcd * 49 + (q >> 5);
    if (ntile >= NTILES) return;
    const int m0 = (q & 31) * 128;
    const int l0 = ntile * BN;

    if (t < 128) {
        xt[t] = x2[m0 + t];
        int gl = l0 + t;
        bool v = gl < NLEAF;
        float bb = v ? bfac[gl] : 0.0f;
        float yy = v ? y2[gl] : 0.0f;
        ybt[t] = make_float2(bb, v ? yy * bb : 1e30f);
    }

    int srcA[4], srcB[4];
#pragma unroll
    for (int j = 0; j < 4; ++j) {
        int slot = j * 256 + t;
        int row = slot >> 3, sl = slot & 7;
        int swz = sl ^ (row & 7);
        srcA[j] = (m0 + row) * 512 + swz * 16;
        int gl = l0 + row; if (gl > NLEAF - 1) gl = NLEAF - 1;
        srcB[j] = gl * 512 + swz * 16;
    }

    f16v acc[2][2];
#pragma unroll
    for (int i = 0; i < 2; ++i)
#pragma unroll
        for (int j = 0; j < 2; ++j)
#pragma unroll
            for (int r = 0; r < 16; ++r) acc[i][j][r] = 0.0f;

    auto stage = [&](int ks, int bsel) {
        char* dst = sm + bsel * 32768;
        const int kb = ks * 128;
#pragma unroll
        for (int j = 0; j < 4; ++j) {
            gload_lds16((const char*)zf + srcA[j] + kb, dst + (j * 256 + w * 64) * 16);
            gload_lds16((const char*)lf + srcB[j] + kb, dst + 16384 + (j * 256 + w * 64) * 16);
        }
    };

    auto compute = [&](int bsel) {
        const char* Ab = sm + bsel * 32768;
        const char* Bb = Ab + 16384;
#pragma unroll
        for (int kk = 0; kk < 4; ++kk) {
            const int cz = kk * 32 + lg2 * 16;
            h8 za[2], lb[2];
#pragma unroll
            for (int f = 0; f < 2; ++f) {
                int ra = wr * 64 + f * 32 + l31;
                za[f] = *(const h8*)(Ab + ra * 128 + (cz ^ ((ra & 7) << 4)));
                int rb = wc * 64 + f * 32 + l31;
                lb[f] = *(const h8*)(Bb + rb * 128 + (cz ^ ((rb & 7) << 4)));
            }
#pragma unroll
            for (int fi = 0; fi < 2; ++fi)
#pragma unroll
                for (int fj = 0; fj < 2; ++fj)
                    acc[fi][fj] = __builtin_amdgcn_mfma_f32_32x32x16_f16(lb[fj], za[fi], acc[fi][fj], 0, 0, 0);
        }
    };

    stage(0, 0);
    __syncthreads();
#pragma unroll
    for (int ks = 0; ks < 4; ++ks) {
        if (ks < 3) stage(ks + 1, (ks + 1) & 1);
        compute(ks & 1);
        __syncthreads();
    }

    float xv[2] = { xt[wr * 64 + l31], xt[wr * 64 + 32 + l31] };
#pragma unroll
    for (int fi = 0; fi < 2; ++fi)
#pragma unroll
        for (int fj = 0; fj < 2; ++fj)
#pragma unroll
            for (int hi = 0; hi < 2; ++hi) {
                float kx[8];
#pragma unroll
                for (int r8 = 0; r8 < 8; ++r8) {
                    int reg = hi * 8 + r8;
                    int L = wc * 64 + fj * 32 + (r8 & 3) + 8 * (r8 >> 2) + 4 * lg2 + 16 * hi;
                    float2 p = ybt[L];
                    float a = acc[fi][fj][reg];
                    kx[r8] = fmaf(p.x, fmaf(-2.0f, a, xv[fi]), p.y);
                }
                float gm = fminf(fminf(fminf(kx[0], kx[1]), fminf(kx[2], kx[3])),
                                 fminf(fminf(kx[4], kx[5]), fminf(kx[6], kx[7])));
                gm = fminf(gm, __shfl_xor(gm, 32, 64));
                if (lg2 == 0) {
                    int g = ntile * 8 + wc * 4 + fj * 2 + hi;
                    _Float16 hgm = (_Float16)fminf(gm, 60000.0f);
                    mins[(size_t)g * BATCH + m0 + wr * 64 + fi * 32 + l31] =
                        __builtin_bit_cast(unsigned short, hgm);
                }
            }
}

// ---------- kernel 2a: partial per-(row,chunk) top-5 of group mins ----------
__global__ __launch_bounds__(256) void select1_k(const unsigned short* __restrict__ mins,
                                                 float* __restrict__ part5) {
    __shared__ float sm5[4][64][5];
    const int w = threadIdx.x >> 6, l = threadIdx.x & 63;
    const int row = blockIdx.x * 64 + l;
    const int jb = w * ((GPC + 3) / 4);
    const int je = min(GPC, jb + (GPC + 3) / 4);
    float t5[5] = {FLT_MAX, FLT_MAX, FLT_MAX, FLT_MAX, FLT_MAX};
    int j = jb;
    for (; j + 4 <= je; j += 4) {
        int g = blockIdx.y * GPC + j;
        float a0 = (g     < NGRP) ? h2f(mins[(size_t)g * BATCH + row]) : FLT_MAX;
        float a1 = (g + 1 < NGRP) ? h2f(mins[(size_t)(g + 1) * BATCH + row]) : FLT_MAX;
        float a2 = (g + 2 < NGRP) ? h2f(mins[(size_t)(g + 2) * BATCH + row]) : FLT_MAX;
        float a3 = (g + 3 < NGRP) ? h2f(mins[(size_t)(g + 3) * BATCH + row]) : FLT_MAX;
        float m4 = fminf(fminf(a0, a1), fminf(a2, a3));
        if (m4 < t5[4]) {
            insert5v(a0, t5); insert5v(a1, t5); insert5v(a2, t5); insert5v(a3, t5);
        }
    }
    for (; j < je; ++j) {
        int g = blockIdx.y * GPC + j;
        float a = (g < NGRP) ? h2f(mins[(size_t)g * BATCH + row]) : FLT_MAX;
        insert5v(a, t5);
    }
#pragma unroll
    for (int q = 0; q < 5; ++q) sm5[w][l][q] = t5[q];
    __syncthreads();
    if (w == 0) {
#pragma unroll
        for (int ww = 1; ww < 4; ++ww)
#pragma unroll
            for (int q = 0; q < 5; ++q) insert5v(sm5[ww][l][q], t5);
#pragma unroll
        for (int q = 0; q < 5; ++q)
            part5[((size_t)row * NCHUNK + blockIdx.y) * 5 + q] = t5[q];
    }
}

// ---------- kernel 2b: merge chunk top-5s -> threshold; zero cnt/ovf/gcnt ----------
__global__ void select_merge_k(const float* __restrict__ part5,
                               float* __restrict__ rowthr, int* __restrict__ cnt,
                               int* __restrict__ ovf, int* __restrict__ gcnt) {
    int idx = blockIdx.x * 256 + threadIdx.x;
    if (idx < NGRP) gcnt[idx] = 0;
    if (idx >= BATCH) return;
    int row = idx;
    float t5[5] = {FLT_MAX, FLT_MAX, FLT_MAX, FLT_MAX, FLT_MAX};
    const float* p = part5 + (size_t)row * NCHUNK * 5;
    for (int s = 0; s < NCHUNK * 5; ++s) insert5v(p[s], t5);
    rowthr[row] = t5[4] + 2e-3f * fabsf(t5[4]) + 1.8e-2f;
    cnt[row] = 0;
    ovf[row] = 0;
}

// ---------- kernel 2c: candidate scan -> per-row list + per-group CSR ----------
__global__ __launch_bounds__(256) void select_scan_k(const unsigned short* __restrict__ mins,
                                                     const float* __restrict__ rowthr,
                                                     int* __restrict__ cnt,
                                                     int* __restrict__ cand,
                                                     int* __restrict__ gcnt,
                                                     unsigned int* __restrict__ glist,
                                                     int* __restrict__ ovf) {
    const int w = threadIdx.x >> 6, l = threadIdx.x & 63;
    const int row = blockIdx.x * 64 + l;
    const float thr = rowthr[row];
    const int jb = w * ((GPC + 3) / 4);
    const int je = min(GPC, jb + (GPC + 3) / 4);
    for (int j = jb; j < je; ++j) {
        int g = blockIdx.y * GPC + j;
        if (g >= NGRP) break;
        float m = h2f(mins[(size_t)g * BATCH + row]);
        if (m <= thr) {
            int c = atomicAdd(&cnt[row], 1);
            if (c < MAXC) {
                cand[row * MAXC + c] = g;
                int s = atomicAdd(&gcnt[g], 1);
                if (s < GCAP) glist[(size_t)g * GCAP + s] = ((unsigned)row << 7) | (unsigned)c;
                else ovf[row] = 1;      // dropped pair -> row handled by fallback
            }
        }
    }
}

// ---------- kernel 3a: group-major exact fp32 keys ----------
// block = group; 16 leaf rows in registers (64 floats/lane, static idx);
// per pair (row,ci): broadcast z reads, dot, write keybuf[row][ci][16].
__global__ __launch_bounds__(256) void recheck_g_k(
        const float* __restrict__ z, const float* __restrict__ leaf,
        const float* __restrict__ x2, const float* __restrict__ y2,
        const float* __restrict__ bfac,
        const int* __restrict__ gcnt, const unsigned int* __restrict__ glist,
        float* __restrict__ keybuf) {
    const int g = blockIdx.x;
    int n = gcnt[g];
    if (n <= 0) return;
    if (n > GCAP) n = GCAP;
    const int t = threadIdx.x, w = t >> 6, l = t & 63;
    const int j = l & 15, q = l >> 4;
    float lr[64];
    const float* lrow = leaf + (size_t)(g * 16 + j) * DIM + q * 64;
#pragma unroll
    for (int tt = 0; tt < 16; ++tt) {
        float4 v = *(const float4*)(lrow + tt * 4);
        lr[tt * 4 + 0] = v.x; lr[tt * 4 + 1] = v.y;
        lr[tt * 4 + 2] = v.z; lr[tt * 4 + 3] = v.w;
    }
    const float yb = y2[g * 16 + j], bb = bfac[g * 16 + j];
    for (int i = w; i < n; i += 4) {
        unsigned int pk = glist[(size_t)g * GCAP + i];
        int row = (int)(pk >> 7), ci = (int)(pk & 127u);
        const float4* z4 = (const float4*)(z + (size_t)row * DIM) + q * 16;
        float d = 0.0f;
#pragma unroll
        for (int tt = 0; tt < 16; ++tt) {
            float4 v = z4[tt];
            d = fmaf(v.x, lr[tt * 4 + 0], d);
            d = fmaf(v.y, lr[tt * 4 + 1], d);
            d = fmaf(v.z, lr[tt * 4 + 2], d);
            d = fmaf(v.w, lr[tt * 4 + 3], d);
        }
        d += __shfl_xor(d, 16, 64);
        d += __shfl_xor(d, 32, 64);
        if (q == 0) {
            float sq = fmaxf(x2[row] + yb - 2.0f * d, 0.0f);
            keybuf[((size_t)row * MAXC + ci) * 16 + j] = sq * bb;
        }
    }
}

// ---------- kernel 3b: per-row merge of candidate keys -> outputs ----------
__global__ __launch_bounds__(256) void final_k(
        const float* __restrict__ keybuf, const int* __restrict__ cand,
        const int* __restrict__ cnt, const int* __restrict__ ovf,
        const float* __restrict__ afac, const int* __restrict__ ids,
        const float* __restrict__ thr, float* __restrict__ out) {
    const int t = threadIdx.x, w = t >> 6, l = t & 63;
    const int row = blockIdx.x * 4 + w;
    if (ovf[row]) return;                 // fallback kernel owns this row
    int nc = cnt[row]; if (nc > MAXC) nc = MAXC;
    u64 t5[5] = {~0ull, ~0ull, ~0ull, ~0ull, ~0ull};
    const float* kb = keybuf + (size_t)row * MAXC * 16;
    const int* cr = cand + row * MAXC;
    for (int idx = l; idx < nc * 16; idx += 64) {
        int ci = idx >> 4, j = idx & 15;
        float key = kb[ci * 16 + j];
        unsigned int id = (unsigned)(cr[ci] * 16 + j);
        u64 pk = ((u64)__float_as_uint(key) << 32) | (u64)id;
        insert5u(pk, t5);
    }
#pragma unroll
    for (int s = 1; s < 64; s <<= 1) {
        u64 o[5];
#pragma unroll
        for (int qq = 0; qq < 5; ++qq) o[qq] = __shfl_xor(t5[qq], s, 64);
        u64 n0 = umin64(t5[0], o[0]);
        u64 n1 = umin64(umin64(t5[1], o[1]), umax64(t5[0], o[0]));
        u64 n2 = umin64(umin64(t5[2], o[2]),
                 umin64(umax64(t5[0], o[1]), umax64(t5[1], o[0])));
        u64 n3 = umin64(umin64(t5[3], o[3]),
                 umin64(umax64(t5[0], o[2]),
                 umin64(umax64(t5[1], o[1]), umax64(t5[2], o[0]))));
        u64 n4 = umin64(umin64(t5[4], o[4]),
                 umin64(umin64(umax64(t5[0], o[3]), umax64(t5[1], o[2])),
                        umin64(umax64(t5[2], o[1]), umax64(t5[3], o[0]))));
        t5[0]=n0; t5[1]=n1; t5[2]=n2; t5[3]=n3; t5[4]=n4;
    }
    if (l == 0) {
        float k0 = __uint_as_float((unsigned)(t5[0] >> 32));
        float u = k0 * afac[row];
        u = fmaxf(u, 1e-7f);
        float dd = log1pf(u + sqrtf(u * (u + 2.0f)));
        out[row] = dd;
        out[BATCH + row] = (dd > thr[0]) ? 1.0f : 0.0f;
#pragma unroll
        for (int qq = 0; qq < 5; ++qq)
            out[2 * BATCH + (size_t)row * 5 + qq] = (float)ids[(unsigned)(t5[qq] & 0xFFFFFFFFull)];
    }
}

// ---------- kernel 3c: row-major exact fallback (GCAP-overflow rows only) ----------
__global__ __launch_bounds__(256) void recheck_fb_k(
        const float* __restrict__ z, const float* __restrict__ leaf,
        const float* __restrict__ x2, const float* __restrict__ y2,
        const float* __restrict__ bfac, const float* __restrict__ afac,
        const int* __restrict__ cnt, const int* __restrict__ cand,
        const int* __restrict__ ovf,
        const int* __restrict__ ids, const float* __restrict__ thr,
        float* __restrict__ out) {
    __shared__ float mk[20];
    __shared__ int   mi[20];
    const int row = blockIdx.x;
    if (ovf[row] == 0) return;
    const int t = threadIdx.x, w = t >> 6, l = t & 63;
    float4 zr = *(const float4*)(z + (size_t)row * DIM + l * 4);
    const float x2r = x2[row];
    int nc = cnt[row]; if (nc > MAXC) nc = MAXC;
    float k5[5]; int i5[5];
#pragma unroll
    for (int q = 0; q < 5; ++q) { k5[q] = FLT_MAX; i5[q] = 0x7FFFFFFF; }
    for (int ci = w; ci < nc; ci += 4) {
        int g = cand[row * MAXC + ci];
#pragma unroll 1
        for (int jj = 0; jj < 16; ++jj) {
            int id = g * 16 + jj;
            if (id >= NLEAF) break;
            float4 lfv = *(const float4*)(leaf + (size_t)id * DIM + l * 4);
            float d = zr.x * lfv.x;
            d = fmaf(zr.y, lfv.y, d); d = fmaf(zr.z, lfv.z, d); d = fmaf(zr.w, lfv.w, d);
#pragma unroll
            for (int s = 1; s < 64; s <<= 1) d += __shfl_xor(d, s, 64);
            float sq = fmaxf(x2r + y2[id] - 2.0f * d, 0.0f);
            float key = sq * bfac[id];
            insert5lex(key, id, k5, i5);
        }
    }
    if (l == 0) {
#pragma unroll
        for (int q = 0; q < 5; ++q) { mk[w * 5 + q] = k5[q]; mi[w * 5 + q] = i5[q]; }
    }
    __syncthreads();
    if (t == 0) {
        float fk[5]; int fi[5];
#pragma unroll
        for (int q = 0; q < 5; ++q) { fk[q] = FLT_MAX; fi[q] = 0x7FFFFFFF; }
        for (int s = 0; s < 20; ++s) insert5lex(mk[s], mi[s], fk, fi);
        float u = fk[0] * afac[row];
        u = fmaxf(u, 1e-7f);
        float dd = log1pf(u + sqrtf(u * (u + 2.0f)));
        out[row] = dd;
        out[BATCH + row] = (dd > thr[0]) ? 1.0f : 0.0f;
#pragma unroll
        for (int q = 0; q < 5; ++q)
            out[2 * BATCH + (size_t)row * 5 + q] = (float)ids[fi[q]];
    }
}

extern "C" void kernel_launch(void* const* d_in, const int* in_sizes, int n_in,
                              void* d_out, int out_size, void* d_ws, size_t ws_size,
                              hipStream_t stream) {
    const float* z    = (const float*)d_in[0];
    const float* leaf = (const float*)d_in[1];
    const int*   ids  = (const int*)d_in[2];
    const float* thr  = (const float*)d_in[3];
    float* out = (float*)d_out;

    char* ws = (char*)d_ws;
    float* x2   = (float*)(ws + 0);
    float* afac = (float*)(ws + 16384);
    float* y2   = (float*)(ws + 32768);
    float* bfac = (float*)(ws + 232768);
    unsigned short* zf = (unsigned short*)(ws + 432768);     // 2 MB   (dead after gemm)
    unsigned short* lf = (unsigned short*)(ws + 2529920);    // 25.6 MB (dead after gemm)
    unsigned short* mins = (unsigned short*)(ws + 28129920); // 25.6 MB (dead after scan)
    int* cnt  = (int*)(ws + 53754496);
    int* ovf  = (int*)(ws + 53770880);
    int* gcnt = (int*)(ws + 53787264);
    int* cand = (int*)(ws + 53803648);              // 2 MB
    float* part5  = (float*)(ws + 55900800);        // 655 KB
    float* rowthr = (float*)(ws + 56556160);
    unsigned int* glist = (unsigned int*)(ws + 56572544);   // 25.6 MB -> ends 82.2 MB
    float* keybuf = (float*)(ws + 432768);          // 33.5 MB, ALIASES zf/lf/mins (all
                                                    // dead before recheck_g_k writes)

    norms_cvt_k<<<(BATCH + NLEAF + 3) / 4, 256, 0, stream>>>(z, leaf, x2, afac, y2, bfac, zf, lf);
    gemm_min_k<<<8 * 49 * 32, 256, 67072, stream>>>(zf, lf, x2, y2, bfac, mins);
    select1_k<<<dim3(BATCH / 64, NCHUNK), 256, 0, stream>>>(mins, part5);
    select_merge_k<<<16, 256, 0, stream>>>(part5, rowthr, cnt, ovf, gcnt);
    select_scan_k<<<dim3(BATCH / 64, NCHUNK), 256, 0, stream>>>(mins, rowthr, cnt, cand, gcnt, glist, ovf);
    recheck_g_k<<<NGRP, 256, 0, stream>>>(z, leaf, x2, y2, bfac, gcnt, glist, keybuf);
    final_k<<<BATCH / 4, 256, 0, stream>>>(keybuf, cand, cnt, ovf, afac, ids, thr, out);
    recheck_fb_k<<<BATCH, 256, 0, stream>>>(z, leaf, x2, y2, bfac, afac, cnt, cand, ovf, ids, thr, out);
}